// Round 1
// baseline (216.556 us; speedup 1.0000x reference)
//
#include <hip/hip_runtime.h>
#include <stdint.h>

// Binary conv via bit-pack + XNOR popcount, zero-padded halo + class-correction.
// A: [32,64,112,112] f32, W: [64,64,3,3] f32 (flat), out: [32,64,112,112] f32.
// sign(x) encoded as bit = signbit(x); dot over 64 ch = 64 - 2*popc(a ^ w).
// Padding: packed buffer has a zeroed 1-word halo (all-bits-0 = all +1 signs);
// the spurious pad contribution Sum_inv(64 - 2*popc(w)) is folded into a
// per-(boundary-class, o) base constant: out = bases[class][o] - 2*s.

#define NN 32
#define CC 64
#define HH 112
#define WW 112
#define OO 64
#define HW (HH*WW)        // 12544
#define NHW (NN*HW)       // 401408

#define PW 114            // padded width  (1-word halo each side)
#define PH 114            // padded height
#define PHW (PW*PH)       // 12996 words per image

#define GPR (WW/4)        // 28  float4-groups per row
#define GPI (HW/4)        // 3136 groups per image
#define NGRP (NHW/4)      // 100352 groups total

#define BLK 256
#define PACK_BLOCKS (NGRP/BLK)   // 392 (conv uses the same grid)

// workspace layout in u64 words:
//   [0,576)        wp      packed weights
//   [1024,1024+288) bases  float[9][64] boundary-class base constants
//   [1536, ...)    ap      zero-padded packed activations (32*12996 words)

__global__ __launch_bounds__(BLK)
void pack_kernel(const float* __restrict__ act, const float* __restrict__ wgt,
                 uint64_t* __restrict__ ap, uint64_t* __restrict__ wp,
                 float* __restrict__ bases) {
    int b = blockIdx.x;
    if (b == PACK_BLOCKS) {
        // ---- zero the halo: 452 words per image (rows 0/113 full + cols 0/113) ----
        for (int i = threadIdx.x; i < NN * 452; i += BLK) {
            int n = i / 452, j = i - n * 452;
            int row, col;
            if (j < PW)          { row = 0;      col = j; }
            else if (j < 2*PW)   { row = PH - 1; col = j - PW; }
            else { int j2 = j - 2*PW; row = 1 + (j2 >> 1); col = (j2 & 1) ? (PW - 1) : 0; }
            ap[(size_t)n * PHW + (size_t)row * PW + col] = 0ull;
        }
        // ---- pack weights: wp[o*9+k] bit i = signbit(W[o][i][kh][kw]) ----
        for (int t = threadIdx.x; t < OO * 9; t += BLK) {
            int o = t / 9, k = t - o * 9;
            uint32_t lo = 0, hi = 0;
            #pragma unroll
            for (int i = 0; i < 64; ++i) {
                uint32_t s = __float_as_uint(wgt[(o * 64 + i) * 9 + k]) >> 31;
                if (i < 32) lo |= s << i;
                else        hi |= s << (i - 32);
            }
            wp[t] = ((uint64_t)hi << 32) | lo;
        }
        __syncthreads();
        // ---- bases[class][o] = 576 - Sum_{k invalid in class} (64 - 2*popc(w_ok)) ----
        if (threadIdx.x < OO) {
            int o = threadIdx.x;
            int contrib[9];
            #pragma unroll
            for (int k = 0; k < 9; ++k)
                contrib[k] = 64 - 2 * (int)__popcll(wp[o * 9 + k]);
            #pragma unroll
            for (int ht = 0; ht < 3; ++ht) {
                #pragma unroll
                for (int wt = 0; wt < 3; ++wt) {
                    int sum = 0;
                    #pragma unroll
                    for (int k = 0; k < 9; ++k) {
                        int kh = k / 3, kw = k - kh * 3;
                        bool inv = (ht == 0 && kh == 0) || (ht == 2 && kh == 2) ||
                                   (wt == 0 && kw == 0) || (wt == 2 && kw == 2);
                        if (inv) sum += contrib[k];
                    }
                    bases[(ht * 3 + wt) * OO + o] = (float)(576 - sum);
                }
            }
        }
        return;
    }
    // ---- pack activations: 4 pixels (float4 across w) per thread ----
    int t = b * BLK + threadIdx.x;               // float4-group id over N*HW/4
    int n = t / GPI;
    int g = t - n * GPI;                         // group index within image = h*28 + w4
    int h = g / GPR;
    int w4 = g - h * GPR;
    const float4* base = (const float4*)act + (size_t)n * CC * GPI + g;
    uint32_t lo[4] = {0, 0, 0, 0}, hi[4] = {0, 0, 0, 0};
    #pragma unroll
    for (int c = 0; c < 64; ++c) {
        float4 v = base[(size_t)c * GPI];        // coalesced: 64 lanes x 16B
        uint32_t s0 = __float_as_uint(v.x) >> 31;
        uint32_t s1 = __float_as_uint(v.y) >> 31;
        uint32_t s2 = __float_as_uint(v.z) >> 31;
        uint32_t s3 = __float_as_uint(v.w) >> 31;
        if (c < 32) {
            lo[0] |= s0 << c; lo[1] |= s1 << c; lo[2] |= s2 << c; lo[3] |= s3 << c;
        } else {
            int cc = c - 32;
            hi[0] |= s0 << cc; hi[1] |= s1 << cc; hi[2] |= s2 << cc; hi[3] |= s3 << cc;
        }
    }
    // padded write: image pixel (h, w4*4+px) -> padded (h+1, w4*4+1+px)
    uint64_t* dst = ap + (size_t)n * PHW + (size_t)(h + 1) * PW + (size_t)(w4 * 4 + 1);
    dst[0] = ((uint64_t)hi[0] << 32) | lo[0];
    dst[1] = ((uint64_t)hi[1] << 32) | lo[1];
    dst[2] = ((uint64_t)hi[2] << 32) | lo[2];
    dst[3] = ((uint64_t)hi[3] << 32) | lo[3];
}

__global__ __launch_bounds__(BLK)
void conv_kernel(const uint64_t* __restrict__ ap, const uint64_t* __restrict__ wp,
                 const float* __restrict__ bases, float* __restrict__ out) {
    int t = blockIdx.x * BLK + threadIdx.x;      // 4 consecutive output pixels
    int n = t / GPI;
    int g = t - n * GPI;
    int h = g / GPR;
    int w4 = g - h * GPR;
    int w0 = w4 * 4;

    // load 3 rows x 6 words (padded rows h..h+2, cols w0..w0+5), 16B-aligned
    uint64_t A[3][6];
    const uint64_t* rb = ap + (size_t)n * PHW + (size_t)h * PW + w0;
    #pragma unroll
    for (int r = 0; r < 3; ++r) {
        const ulonglong2* p = (const ulonglong2*)(rb + (size_t)r * PW);
        ulonglong2 u0 = p[0], u1 = p[1], u2 = p[2];
        A[r][0] = u0.x; A[r][1] = u0.y;
        A[r][2] = u1.x; A[r][3] = u1.y;
        A[r][4] = u2.x; A[r][5] = u2.y;
    }

    int ht = (h == 0) ? 0 : ((h == HH - 1) ? 2 : 1);
    const float* bp0;
    const float* bp1;
    const float* bp2;
    const float* bp3;
    {
        int wt0 = (w0 == 0) ? 0 : 1;
        int wt3 = (w0 + 3 == WW - 1) ? 2 : 1;
        bp0 = bases + (ht * 3 + wt0) * OO;
        bp1 = bases + (ht * 3 + 1) * OO;
        bp2 = bases + (ht * 3 + 1) * OO;
        bp3 = bases + (ht * 3 + wt3) * OO;
    }

    float* op = out + (size_t)n * (OO * HW) + (size_t)h * WW + w0;
    #pragma unroll 2
    for (int o = 0; o < OO; ++o) {
        const uint64_t* wk = wp + o * 9;         // wave-uniform -> scalar loads
        int s0 = 0, s1 = 0, s2 = 0, s3 = 0;
        #pragma unroll
        for (int kh = 0; kh < 3; ++kh) {
            #pragma unroll
            for (int kw = 0; kw < 3; ++kw) {
                uint64_t wv = wk[kh * 3 + kw];
                s0 += __popcll(A[kh][kw    ] ^ wv);
                s1 += __popcll(A[kh][kw + 1] ^ wv);
                s2 += __popcll(A[kh][kw + 2] ^ wv);
                s3 += __popcll(A[kh][kw + 3] ^ wv);
            }
        }
        float4 v;
        v.x = bp0[o] - 2.0f * (float)s0;
        v.y = bp1[o] - 2.0f * (float)s1;
        v.z = bp2[o] - 2.0f * (float)s2;
        v.w = bp3[o] - 2.0f * (float)s3;
        *(float4*)(op + (size_t)o * HW) = v;     // coalesced 16B store
    }
}

extern "C" void kernel_launch(void* const* d_in, const int* in_sizes, int n_in,
                              void* d_out, int out_size, void* d_ws, size_t ws_size,
                              hipStream_t stream) {
    const float* act = (const float*)d_in[0];
    const float* wgt = (const float*)d_in[1];
    float* out = (float*)d_out;

    uint64_t* wp = (uint64_t*)d_ws;              // 576 words (reserve 1024)
    float* bases = (float*)(wp + 1024);          // 9*64 floats = 2304 B (reserve 4 KB)
    uint64_t* ap = wp + 1536;                    // 32*12996 words ~= 3.33 MB

    pack_kernel<<<PACK_BLOCKS + 1, BLK, 0, stream>>>(act, wgt, ap, wp, bases);
    conv_kernel<<<PACK_BLOCKS, BLK, 0, stream>>>(ap, wp, bases, out);
}